// Round 13
// baseline (45.806 us; speedup 1.0000x reference)
//
#include <hip/hip_runtime.h>

// B=2, N_mm=64, N_a=N_v=256, DIM=512, H=8, hd=64, scale=1/8.
// Factorized: softmax over (i,j) grid with logits Av_i+Aa_j, values vv_i+va_j
// = SUM of two independently-normalized 256-key attentions:
//   out = (Σ_i softmax_i(Av) vv_i) + (Σ_j softmax_j(Aa) va_j).
//
// Lessons (measured R2-R12):
//  * MFMA operands only from LDS, coalesced staging (R10: scattered = 96us)
//  * No cross-kernel slab handoff; contiguous f32 hv/ha crossing is free
//  * No persistent spin barriers (R6/R8: ~35us each)
//  * R11/R12: register-staged prefetch gets SUNK by the compiler (VGPR=96,
//    loads serialized per step behind syncthreads vmcnt(0) drain) ->
//    8.3MB min-fetch at ~190GB/s = 44us. Fix: global_load_lds (width 16,
//    un-sinkable, vmcnt-counted) + fp32 LDS staging (convert at frag read)
//    + raw s_barrier with COUNTED vmcnt(8) so next step stays in flight.
//
// K1: per-(b,h,side) fused proj+attention, 32 blocks x 512 thr, 128KB LDS.
// K2: out = (hv+ha) @ Wproj.T + bproj, 16 blocks x 256 thr.

typedef _Float16 f16x8 __attribute__((ext_vector_type(8)));
typedef _Float16 f16x4 __attribute__((ext_vector_type(4)));
typedef float f32x4 __attribute__((ext_vector_type(4)));

__device__ __forceinline__ void gload_lds16(const void* g, void* l)
{
  __builtin_amdgcn_global_load_lds(
      (const __attribute__((address_space(1))) void*)g,
      (__attribute__((address_space(3))) void*)l, 16, 0, 0);
}

__device__ __forceinline__ f16x8 cvt2(float4 a, float4 b)
{
  f16x8 h = {(_Float16)a.x, (_Float16)a.y, (_Float16)a.z, (_Float16)a.w,
             (_Float16)b.x, (_Float16)b.y, (_Float16)b.z, (_Float16)b.w};
  return h;
}

// fp32 staged tile: rows of 32 floats (8 chunks x 16B), source-swizzled
// chunk' = chunk ^ (row&7). Fragment = global chunks {2kg, 2kg+1} of a row.
__device__ __forceinline__ f16x8 frag(const float* base, int r, int kg2)
{
  int s0 = kg2 ^ (r & 7);
  float4 a = *reinterpret_cast<const float4*>(base + r * 32 + s0 * 4);
  float4 b = *reinterpret_cast<const float4*>(base + r * 32 + (s0 ^ 1) * 4);
  return cvt2(a, b);
}

// ---------------------------------------------------------------------------
// K1 LDS map (bytes, 131072 total):
//  phase 1: Xb[2] @ 0 / 32768 (each 256 rows x 128B = X keys, k-window 32f)
//           Wb[2] @ 65536 / 98304 (rows 0-63 WkvK, 64-127 WkvV, 128-191 Wq,
//                                  192-255 xmm)
//  phase 2 overlay: Kl f16[256][64] @0; Vl f16[64][256] @32768;
//           Ql f16[64][64] @65536; P f16[64][256] @73728; stats @106496.
// Phase 1: 16 K-steps (BK=32). Per step: issue next step's global_load_lds
// (8/wave), s_waitcnt vmcnt(8), s_barrier, frag-convert+MFMA (18/wave),
// s_barrier. Accumulators live in registers across all steps.
// ---------------------------------------------------------------------------
__global__ __launch_bounds__(512, 2) void fused_bh_kernel(
    const float* __restrict__ xmm, const float* __restrict__ xa,
    const float* __restrict__ xv, const float* __restrict__ Wq,
    const float* __restrict__ Wkv, float* __restrict__ hv,
    float* __restrict__ ha)
{
  __shared__ __align__(16) char smem[131072];
  char* ldsc = smem;
  _Float16* Kl = (_Float16*)smem;                  // [256][64]
  _Float16* Vl = (_Float16*)(smem + 32768);        // [64][256] (V^T)
  _Float16* Ql = (_Float16*)(smem + 65536);        // [64][64]
  _Float16* P  = (_Float16*)(smem + 73728);        // [64][256]
  float* m_s  = (float*)(smem + 106496);           // [8][64]
  float* l_s  = m_s + 512;                         // [8][64]
  float* Mtot = l_s + 512;                         // [64]
  float* Ltot = Mtot + 64;                         // [64]

  const int bid = blockIdx.x;     // b*16 + h*2 + side
  const int side = bid & 1;
  const int h = (bid >> 1) & 7;
  const int b = bid >> 4;

  const int tid = threadIdx.x;
  const int w = tid >> 6;         // wave 0..7
  const int lane = tid & 63;
  const int l15 = lane & 15;
  const int kg = lane >> 4;       // 0..3
  const int kg2 = kg * 2;
  const int nf = w >> 1;

  const float* X = (side ? xa : xv) + (size_t)b * 256 * 512;
  const float* xmm_b = xmm + (size_t)b * 64 * 512;

  // ---- per-lane source pointers for global_load_lds (source-swizzled) ----
  const int rl = lane >> 3;                  // row within 8-row call group
  const int swzf = ((lane & 7) ^ rl) * 4;    // swizzled chunk, float offset
  const float* xg[4];
  const float* wg[4];
  {
    const int band = w >> 1;                 // wave-uniform W source band
    #pragma unroll
    for (int c = 0; c < 4; ++c) {
      const int rr = w * 32 + c * 8 + rl;    // global staging row 0..255
      xg[c] = X + (size_t)rr * 512 + swzf;
      const float* p;
      if (band == 0)      p = Wkv + (size_t)(h * 64 + rr) * 1024 + side * 512;
      else if (band == 1) p = Wkv + (size_t)(512 + h * 64 + (rr - 64)) * 1024 + side * 512;
      else if (band == 2) p = Wq + (size_t)(h * 64 + (rr - 128)) * 512;
      else                p = xmm_b + (size_t)(rr - 192) * 512;
      wg[c] = p + swzf;
    }
  }

#define ISSUE(S, BUF)                                                        \
  {                                                                          \
    const int ko_ = (S) * 32;                                                \
    char* xb_ = ldsc + (size_t)(BUF) * 32768;                                \
    char* wb_ = ldsc + 65536 + (size_t)(BUF) * 32768;                        \
    _Pragma("unroll")                                                        \
    for (int c = 0; c < 4; ++c) {                                            \
      gload_lds16(xg[c] + ko_, xb_ + (w * 4 + c) * 1024);                    \
      gload_lds16(wg[c] + ko_, wb_ + (w * 4 + c) * 1024);                    \
    }                                                                        \
  }

  f32x4 ak[2][4] = {};            // K acc [e][df]
  f32x4 avv[2][4] = {};           // V acc
  f32x4 aq[2] = {};               // q acc

  ISSUE(0, 0);
  for (int s = 0; s < 16; ++s) {
    const int cur = s & 1;
    if (s < 15) {
      ISSUE(s + 1, (s + 1) & 1);
      asm volatile("s_waitcnt vmcnt(8)" ::: "memory");  // cur step landed
    } else {
      asm volatile("s_waitcnt vmcnt(0)" ::: "memory");
    }
    asm volatile("s_barrier" ::: "memory");             // all waves' data in

    const float* Xc = (const float*)(ldsc + (size_t)cur * 32768);
    const float* Wc = (const float*)(ldsc + 65536 + (size_t)cur * 32768);

    f16x8 xaf0 = frag(Xc, (2 * w + 0) * 16 + l15, kg2);
    f16x8 xaf1 = frag(Xc, (2 * w + 1) * 16 + l15, kg2);
    f16x8 xqa  = frag(Wc, 192 + nf * 16 + l15, kg2);
    #pragma unroll
    for (int df = 0; df < 4; ++df) {
      f16x8 wkB = frag(Wc, df * 16 + l15, kg2);
      f16x8 wvB = frag(Wc, 64 + df * 16 + l15, kg2);
      ak[0][df] = __builtin_amdgcn_mfma_f32_16x16x32_f16(xaf0, wkB, ak[0][df], 0, 0, 0);
      ak[1][df] = __builtin_amdgcn_mfma_f32_16x16x32_f16(xaf1, wkB, ak[1][df], 0, 0, 0);
      avv[0][df] = __builtin_amdgcn_mfma_f32_16x16x32_f16(xaf0, wvB, avv[0][df], 0, 0, 0);
      avv[1][df] = __builtin_amdgcn_mfma_f32_16x16x32_f16(xaf1, wvB, avv[1][df], 0, 0, 0);
    }
    #pragma unroll
    for (int e = 0; e < 2; ++e) {
      f16x8 wqB = frag(Wc, 128 + ((2 * w + e) & 3) * 16 + l15, kg2);
      aq[e] = __builtin_amdgcn_mfma_f32_16x16x32_f16(xqa, wqB, aq[e], 0, 0, 0);
    }
    asm volatile("s_barrier" ::: "memory");             // reads done
  }

  // ---- epilogue: fragments -> Kl / Vl(transposed) / Ql (verified maps) ----
  #pragma unroll
  for (int e = 0; e < 2; ++e) {
    const int kf = 2 * w + e;
    #pragma unroll
    for (int df = 0; df < 4; ++df) {
      const int d = df * 16 + l15;
      const int dch = d >> 3;
      #pragma unroll
      for (int r = 0; r < 4; ++r) {
        const int key = kf * 16 + kg * 4 + r;
        Kl[key * 64 + ((dch ^ (key & 7)) * 8) + (d & 7)] =
            (_Float16)ak[e][df][r];
      }
      const int chv = kf * 2 + (kg >> 1);
      f16x4 vv4 = {(_Float16)avv[e][df][0], (_Float16)avv[e][df][1],
                   (_Float16)avv[e][df][2], (_Float16)avv[e][df][3]};
      *reinterpret_cast<f16x4*>(
          &Vl[d * 256 + ((chv ^ (d & 7)) * 8) + (kg & 1) * 4]) = vv4;
    }
    const int dq = ((2 * w + e) & 3) * 16 + l15;
    #pragma unroll
    for (int r = 0; r < 4; ++r) {
      const int n = nf * 16 + kg * 4 + r;
      Ql[n * 64 + (((dq >> 3) ^ (n & 7)) * 8) + (dq & 7)] =
          (_Float16)(aq[e][r] * 0.125f);
    }
  }
  __syncthreads();

  // ---- phase 2: attention (R7/R12-verified body) ----
  f16x8 qb[4][2];
  #pragma unroll
  for (int qf = 0; qf < 4; ++qf)
    #pragma unroll
    for (int ks = 0; ks < 2; ++ks)
      qb[qf][ks] = *reinterpret_cast<const f16x8*>(
          &Ql[(qf * 16 + l15) * 64 + (((ks * 4 + kg) ^ (l15 & 7)) * 8)]);

  f32x4 st[2][4] = {};
  #pragma unroll
  for (int kf = 0; kf < 2; ++kf) {
    int krow = w * 32 + kf * 16 + l15;
    #pragma unroll
    for (int ks = 0; ks < 2; ++ks) {
      f16x8 af = *reinterpret_cast<const f16x8*>(
          &Kl[krow * 64 + (((ks * 4 + kg) ^ (l15 & 7)) * 8)]);
      #pragma unroll
      for (int qf = 0; qf < 4; ++qf)
        st[kf][qf] = __builtin_amdgcn_mfma_f32_16x16x32_f16(
            af, qb[qf][ks], st[kf][qf], 0, 0, 0);
    }
  }
  // st[kf][qf][r] = S[key=w*32+kf*16+4*kg+r][q=qf*16+l15]

  float mx[4];
  #pragma unroll
  for (int qf = 0; qf < 4; ++qf) {
    float m = st[0][qf][0];
    #pragma unroll
    for (int kf = 0; kf < 2; ++kf)
      #pragma unroll
      for (int r = 0; r < 4; ++r) m = fmaxf(m, st[kf][qf][r]);
    m = fmaxf(m, __shfl_xor(m, 16));
    m = fmaxf(m, __shfl_xor(m, 32));
    mx[qf] = m;
  }
  if (kg == 0) {
    #pragma unroll
    for (int qf = 0; qf < 4; ++qf) m_s[w * 64 + qf * 16 + l15] = mx[qf];
  }
  __syncthreads();
  if (tid < 64) {
    float M = m_s[tid];
    #pragma unroll
    for (int w2 = 1; w2 < 8; ++w2) M = fmaxf(M, m_s[w2 * 64 + tid]);
    Mtot[tid] = M;
  }
  __syncthreads();

  #pragma unroll
  for (int qf = 0; qf < 4; ++qf) {
    float M = Mtot[qf * 16 + l15];
    float ls = 0.f;
    #pragma unroll
    for (int kf = 0; kf < 2; ++kf)
      #pragma unroll
      for (int r = 0; r < 4; ++r) {
        float e = __expf(st[kf][qf][r] - M);
        st[kf][qf][r] = e;
        ls += e;
      }
    ls += __shfl_xor(ls, 16);
    ls += __shfl_xor(ls, 32);
    if (kg == 0) l_s[w * 64 + qf * 16 + l15] = ls;
    #pragma unroll
    for (int kf = 0; kf < 2; ++kf) {
      int q = qf * 16 + l15;
      int chunk = w * 4 + kf * 2 + (kg >> 1);
      f16x4 pk = {(_Float16)st[kf][qf][0], (_Float16)st[kf][qf][1],
                  (_Float16)st[kf][qf][2], (_Float16)st[kf][qf][3]};
      *reinterpret_cast<f16x4*>(
          &P[q * 256 + ((chunk ^ (q & 7)) * 8) + (kg & 1) * 4]) = pk;
    }
  }
  __syncthreads();
  if (tid < 64) {
    float L = l_s[tid];
    #pragma unroll
    for (int w2 = 1; w2 < 8; ++w2) L += l_s[w2 * 64 + tid];
    Ltot[tid] = L;
  }
  __syncthreads();

  // PV: wave owns (qf = w&3, d-frags 2*(w>>2)+{0,1}), all 256 keys
  const int qf = w & 3;
  const int d0 = (w >> 2) * 2;
  f32x4 oc[2] = {};
  #pragma unroll
  for (int ks = 0; ks < 8; ++ks) {
    f16x8 pa = *reinterpret_cast<const f16x8*>(
        &P[(qf * 16 + l15) * 256 + (((ks * 4 + kg) ^ (l15 & 7)) * 8)]);
    #pragma unroll
    for (int j = 0; j < 2; ++j) {
      int d = (d0 + j) * 16 + l15;
      f16x8 vb = *reinterpret_cast<const f16x8*>(
          &Vl[d * 256 + (((ks * 4 + kg) ^ (d & 7)) * 8)]);
      oc[j] = __builtin_amdgcn_mfma_f32_16x16x32_f16(pa, vb, oc[j], 0, 0, 0);
    }
  }

  float* houtS = side ? ha : hv;
  #pragma unroll
  for (int j = 0; j < 2; ++j)
    #pragma unroll
    for (int r = 0; r < 4; ++r) {
      int q = qf * 16 + kg * 4 + r;
      int d = (d0 + j) * 16 + l15;
      houtS[(size_t)(b * 64 + q) * 512 + h * 64 + d] =
          oc[j][r] * (1.0f / Ltot[q]);
    }
#undef ISSUE
}

// ---------------------------------------------------------------------------
// K2: out = (hv + ha) @ Wproj.T + bproj. 64x64 MFMA tiles, 16 blocks x 256.
// ---------------------------------------------------------------------------
__device__ __forceinline__ void stage_sum_f16(
    const float* __restrict__ g, const float* __restrict__ g2, int ld,
    int base, int k0, _Float16* __restrict__ lds, int sr, int sq)
{
  const float* p = &g[(size_t)(base + sr) * ld + k0 + sq * 16];
  const float* p2 = g2 ? &g2[(size_t)(base + sr) * ld + k0 + sq * 16] : nullptr;
  float4 v[4];
  #pragma unroll
  for (int i = 0; i < 4; ++i) {
    v[i] = *reinterpret_cast<const float4*>(p + 4 * i);
    if (p2) {
      float4 u = *reinterpret_cast<const float4*>(p2 + 4 * i);
      v[i].x += u.x; v[i].y += u.y; v[i].z += u.z; v[i].w += u.w;
    }
  }
  f16x8 h0 = {(_Float16)v[0].x, (_Float16)v[0].y, (_Float16)v[0].z, (_Float16)v[0].w,
              (_Float16)v[1].x, (_Float16)v[1].y, (_Float16)v[1].z, (_Float16)v[1].w};
  f16x8 h1 = {(_Float16)v[2].x, (_Float16)v[2].y, (_Float16)v[2].z, (_Float16)v[2].w,
              (_Float16)v[3].x, (_Float16)v[3].y, (_Float16)v[3].z, (_Float16)v[3].w};
  int c0 = (sq * 2) ^ (sr & 7);
  int c1 = (sq * 2 + 1) ^ (sr & 7);
  *reinterpret_cast<f16x8*>(&lds[sr * 64 + c0 * 8]) = h0;
  *reinterpret_cast<f16x8*>(&lds[sr * 64 + c1 * 8]) = h1;
}

__global__ __launch_bounds__(256) void proj_out_kernel(
    const float* __restrict__ hv, const float* __restrict__ ha,
    const float* __restrict__ Wproj, const float* __restrict__ bproj,
    float* __restrict__ out)
{
  __shared__ _Float16 As[64 * 64];
  __shared__ _Float16 Ws[64 * 64];
  const int bm = (int)(blockIdx.x >> 3) * 64;
  const int bn = (int)(blockIdx.x & 7) * 64;
  const int tid = threadIdx.x;
  const int lane = tid & 63;
  const int w = tid >> 6;
  const int wm = w >> 1, wn = w & 1;
  const int sr = tid >> 2;
  const int sq = tid & 3;

  f32x4 acc[2][2] = {};
  const int cl = lane & 15;
  const int kg = lane >> 4;

  for (int k0 = 0; k0 < 512; k0 += 64) {
    __syncthreads();
    stage_sum_f16(hv, ha, 512, bm, k0, As, sr, sq);
    stage_sum_f16(Wproj, nullptr, 512, bn, k0, Ws, sr, sq);
    __syncthreads();
    #pragma unroll
    for (int ks = 0; ks < 2; ++ks) {
      f16x8 af[2], bf[2];
      #pragma unroll
      for (int mi = 0; mi < 2; ++mi) {
        int row = wm * 32 + mi * 16 + cl;
        int ch = (ks * 4 + kg) ^ (row & 7);
        af[mi] = *reinterpret_cast<const f16x8*>(&As[row * 64 + ch * 8]);
      }
      #pragma unroll
      for (int ni = 0; ni < 2; ++ni) {
        int col = wn * 32 + ni * 16 + cl;
        int ch = (ks * 4 + kg) ^ (col & 7);
        bf[ni] = *reinterpret_cast<const f16x8*>(&Ws[col * 64 + ch * 8]);
      }
      #pragma unroll
      for (int mi = 0; mi < 2; ++mi)
        #pragma unroll
        for (int ni = 0; ni < 2; ++ni)
          acc[mi][ni] = __builtin_amdgcn_mfma_f32_16x16x32_f16(
              af[mi], bf[ni], acc[mi][ni], 0, 0, 0);
    }
  }

  #pragma unroll
  for (int mi = 0; mi < 2; ++mi)
    #pragma unroll
    for (int ni = 0; ni < 2; ++ni) {
      int row0 = bm + wm * 32 + mi * 16 + kg * 4;
      int col = bn + wn * 32 + ni * 16 + cl;
      float bv = bproj[col];
      #pragma unroll
      for (int r = 0; r < 4; ++r)
        out[(size_t)(row0 + r) * 512 + col] = acc[mi][ni][r] + bv;
    }
}

extern "C" void kernel_launch(void* const* d_in, const int* in_sizes, int n_in,
                              void* d_out, int out_size, void* d_ws, size_t ws_size,
                              hipStream_t stream) {
  const float* xmm   = (const float*)d_in[0];  // [2,64,512]
  const float* xa    = (const float*)d_in[1];  // [2,256,512]
  const float* xv    = (const float*)d_in[2];  // [2,256,512]
  const float* Wq    = (const float*)d_in[3];  // [512,512]
  const float* Wkv   = (const float*)d_in[4];  // [1024,1024]
  const float* Wproj = (const float*)d_in[5];  // [512,512]
  const float* bproj = (const float*)d_in[6];  // [512]
  float* out = (float*)d_out;                  // [2,64,512]
  float* hv = (float*)d_ws;                    // [128][512] f32
  float* ha = hv + 65536;                      // [128][512] f32

  fused_bh_kernel<<<32, 512, 0, stream>>>(xmm, xa, xv, Wq, Wkv, hv, ha);
  proj_out_kernel<<<16, 256, 0, stream>>>(hv, ha, Wproj, bproj, out);
}

// Round 14
// 35.560 us; speedup vs baseline: 1.2881x; 1.2881x over previous
//
#include <hip/hip_runtime.h>

// B=2, N_mm=64, N_a=N_v=256, DIM=512, H=8, hd=64, scale=1/8.
// Factorized: softmax over (i,j) grid with logits Av_i+Aa_j, values vv_i+va_j
// = SUM of two independently-normalized 256-key attentions:
//   out = (Σ_i softmax_i(Av) vv_i) + (Σ_j softmax_j(Aa) va_j).
//
// Measured structure facts (R2-R13):
//  * 3-kernel pipeline is the right shape (34.6us best). Fused small-grid
//    variants are per-CU-bandwidth-bound (~1MB/block on 32 CUs ≈ 40us)
//    regardless of staging mechanism (reg-prefetch / global_load_lds).
//  * Persistent spin barriers: ~35us each. Dead end.
//  * attn steady-state = 4.7us (R9 3x ablation).
//  * THIS ROUND: K1 epilogue stores made contiguous (LDS round-trip per
//    64x64 C-tile -> coalesced 16B stores, V-tiles transposed in LDS), so
//    slabs are full clean lines instead of 2B-scattered partial sectors.
//
// K1: q/pv/pa projections -> f16 slabs (272 blocks x 256 thr)
// K2: attention (32 blocks x 512 thr), slabs staged to LDS coalesced
// K3: out = (hv+ha) @ Wproj.T + bproj (16 blocks x 256 thr)
//
// Workspace (f16 units):
//   Q16 : [b][h][n(64)][d(64)]          q*scale
//   K16 : [side][b][h][key(256)][d(64)]
//   VT16: [side][b][h][d(64)][key(256)]
//   hv/ha: two f32 [128][512] per-side outputs at OHOUT16.

#define OQ16   0
#define OK16   65536
#define OVT16  589824
#define SIDESZ 262144
#define OHOUT16 1114112

typedef _Float16 f16x8 __attribute__((ext_vector_type(8)));
typedef _Float16 f16x4 __attribute__((ext_vector_type(4)));
typedef float f32x4 __attribute__((ext_vector_type(4)));

// ---- fp32 -> swizzled f16 LDS staging (16B-chunk XOR swizzle) -------------
__device__ __forceinline__ void stage_tile_f16(
    const float* __restrict__ g, const float* __restrict__ g2, int ld,
    int base, int k0, _Float16* __restrict__ lds, int sr, int sq)
{
  const float* p = &g[(size_t)(base + sr) * ld + k0 + sq * 16];
  float4 v0 = *reinterpret_cast<const float4*>(p);
  float4 v1 = *reinterpret_cast<const float4*>(p + 4);
  float4 v2 = *reinterpret_cast<const float4*>(p + 8);
  float4 v3 = *reinterpret_cast<const float4*>(p + 12);
  if (g2) {
    const float* p2 = &g2[(size_t)(base + sr) * ld + k0 + sq * 16];
    float4 u0 = *reinterpret_cast<const float4*>(p2);
    float4 u1 = *reinterpret_cast<const float4*>(p2 + 4);
    float4 u2 = *reinterpret_cast<const float4*>(p2 + 8);
    float4 u3 = *reinterpret_cast<const float4*>(p2 + 12);
    v0.x += u0.x; v0.y += u0.y; v0.z += u0.z; v0.w += u0.w;
    v1.x += u1.x; v1.y += u1.y; v1.z += u1.z; v1.w += u1.w;
    v2.x += u2.x; v2.y += u2.y; v2.z += u2.z; v2.w += u2.w;
    v3.x += u3.x; v3.y += u3.y; v3.z += u3.z; v3.w += u3.w;
  }
  f16x8 h0 = {(_Float16)v0.x, (_Float16)v0.y, (_Float16)v0.z, (_Float16)v0.w,
              (_Float16)v1.x, (_Float16)v1.y, (_Float16)v1.z, (_Float16)v1.w};
  f16x8 h1 = {(_Float16)v2.x, (_Float16)v2.y, (_Float16)v2.z, (_Float16)v2.w,
              (_Float16)v3.x, (_Float16)v3.y, (_Float16)v3.z, (_Float16)v3.w};
  int c0 = (sq * 2) ^ (sr & 7);
  int c1 = (sq * 2 + 1) ^ (sr & 7);
  *reinterpret_cast<f16x8*>(&lds[sr * 64 + c0 * 8]) = h0;
  *reinterpret_cast<f16x8*>(&lds[sr * 64 + c1 * 8]) = h1;
}

// ---- MFMA f16 64x64 GEMM tile: C = A[.,512] @ W[.,512]^T ------------------
// MODE 0: q -> f16*1/8 Q16 slab (contiguous stores via LDS round-trip)
// MODE 1: kv -> K16 (row-major) / VT16 (transposed) slabs, contiguous stores
// MODE 2: f32 + bias direct (A = A + A2 summed at staging)
template <int MODE>
__device__ __forceinline__ void mfma_gemm64(
    const float* __restrict__ A, const float* __restrict__ A2, int lda,
    const float* __restrict__ W, int ldw,
    int bm, int bn, int side,
    _Float16* __restrict__ ws16,
    float* __restrict__ Cf, int ldc, const float* __restrict__ bias)
{
  __shared__ __align__(16) _Float16 As[64 * 64];   // 8 KB (reused as Ct)
  __shared__ __align__(16) _Float16 Ws[64 * 64];   // 8 KB
  const int tid = threadIdx.x;
  const int lane = tid & 63;
  const int w = tid >> 6;
  const int wm = w >> 1, wn = w & 1;
  const int sr = tid >> 2;
  const int sq = tid & 3;

  f32x4 acc[2][2] = {};
  const int cl = lane & 15;
  const int kg = lane >> 4;

  for (int k0 = 0; k0 < 512; k0 += 64) {
    __syncthreads();
    stage_tile_f16(A, A2, lda, bm, k0, As, sr, sq);
    stage_tile_f16(W, nullptr, ldw, bn, k0, Ws, sr, sq);
    __syncthreads();
    #pragma unroll
    for (int ks = 0; ks < 2; ++ks) {
      f16x8 af[2], bf[2];
      #pragma unroll
      for (int mi = 0; mi < 2; ++mi) {
        int row = wm * 32 + mi * 16 + cl;
        int ch = (ks * 4 + kg) ^ (row & 7);
        af[mi] = *reinterpret_cast<const f16x8*>(&As[row * 64 + ch * 8]);
      }
      #pragma unroll
      for (int ni = 0; ni < 2; ++ni) {
        int col = wn * 32 + ni * 16 + cl;
        int ch = (ks * 4 + kg) ^ (col & 7);
        bf[ni] = *reinterpret_cast<const f16x8*>(&Ws[col * 64 + ch * 8]);
      }
      #pragma unroll
      for (int mi = 0; mi < 2; ++mi)
        #pragma unroll
        for (int ni = 0; ni < 2; ++ni)
          acc[mi][ni] = __builtin_amdgcn_mfma_f32_16x16x32_f16(
              af[mi], bf[ni], acc[mi][ni], 0, 0, 0);
    }
  }

  if (MODE == 2) {
    #pragma unroll
    for (int mi = 0; mi < 2; ++mi)
      #pragma unroll
      for (int ni = 0; ni < 2; ++ni) {
        int row0 = bm + wm * 32 + mi * 16 + kg * 4;
        int col = bn + wn * 32 + ni * 16 + cl;
        float bv = bias ? bias[col] : 0.f;
        #pragma unroll
        for (int r = 0; r < 4; ++r)
          Cf[(size_t)(row0 + r) * ldc + col] = acc[mi][ni][r] + bv;
      }
    return;
  }

  // ---- contiguous-store epilogue via LDS round-trip ----
  __syncthreads();                       // done reading As/Ws
  _Float16* Ct = As;                     // [64][64] swizzled
  const bool vpart = (MODE == 1) && (bn >= 512);
  if (!vpart) {
    // row-major Ct[row][col] (scale folded for MODE 0)
    #pragma unroll
    for (int mi = 0; mi < 2; ++mi)
      #pragma unroll
      for (int ni = 0; ni < 2; ++ni) {
        int lcol = wn * 32 + ni * 16 + cl;
        int cch = lcol >> 3;
        #pragma unroll
        for (int r = 0; r < 4; ++r) {
          int rr = wm * 32 + mi * 16 + kg * 4 + r;
          float v = acc[mi][ni][r];
          if (MODE == 0) v *= 0.125f;
          Ct[rr * 64 + ((cch ^ (rr & 7)) * 8) + (lcol & 7)] = (_Float16)v;
        }
      }
  } else {
    // transposed Ct[col][row]: 4 consecutive rows -> contiguous f16x4
    #pragma unroll
    for (int mi = 0; mi < 2; ++mi)
      #pragma unroll
      for (int ni = 0; ni < 2; ++ni) {
        int lcol = wn * 32 + ni * 16 + cl;
        int lrow0 = wm * 32 + mi * 16 + kg * 4;
        int rch = lrow0 >> 3;
        f16x4 v4 = {(_Float16)acc[mi][ni][0], (_Float16)acc[mi][ni][1],
                    (_Float16)acc[mi][ni][2], (_Float16)acc[mi][ni][3]};
        *reinterpret_cast<f16x4*>(
            &Ct[lcol * 64 + ((rch ^ (lcol & 7)) * 8) + (lrow0 & 7)]) = v4;
      }
  }
  __syncthreads();

  // readback rows (contiguous) -> coalesced 16B global stores
  const int r2 = tid >> 2;               // 0..63 (Ct row)
  #pragma unroll
  for (int s = 0; s < 2; ++s) {
    int ch = (tid & 3) + s * 4;          // chunks 0..3 then 4..7
    f16x8 val = *reinterpret_cast<const f16x8*>(
        &Ct[r2 * 64 + ((ch ^ (r2 & 7)) * 8)]);
    if (MODE == 0) {
      int rowg = bm + r2;
      int b = rowg >> 6, n = rowg & 63, h = bn >> 6;
      *reinterpret_cast<f16x8*>(
          &ws16[OQ16 + (((size_t)b * 8 + h) * 64 + n) * 64 + ch * 8]) = val;
    } else if (!vpart) {
      int rowg = bm + r2;
      int b = rowg >> 8, key = rowg & 255, h = bn >> 6;
      *reinterpret_cast<f16x8*>(
          &ws16[OK16 + (size_t)side * SIDESZ +
                (((size_t)b * 8 + h) * 256 + key) * 64 + ch * 8]) = val;
    } else {
      int dp0 = bn - 512;
      int b = bm >> 8, h = dp0 >> 6, keyb = bm & 255;
      *reinterpret_cast<f16x8*>(
          &ws16[OVT16 + (size_t)side * SIDESZ +
                (((size_t)b * 8 + h) * 64 + r2) * 256 + keyb + ch * 8]) = val;
    }
  }
}

// K1: fused q / pv / pa projections. 272 blocks x 256 threads.
__global__ __launch_bounds__(256) void fused_proj_kernel(
    const float* __restrict__ xmm, const float* __restrict__ xa,
    const float* __restrict__ xv, const float* __restrict__ Wq,
    const float* __restrict__ Wkv, _Float16* __restrict__ ws16)
{
  const int id = blockIdx.x;
  if (id < 16) {
    mfma_gemm64<0>(xmm, nullptr, 512, Wq, 512, (id >> 3) * 64, (id & 7) * 64,
                   0, ws16, nullptr, 0, nullptr);
  } else if (id < 144) {
    int t = id - 16;
    mfma_gemm64<1>(xv, nullptr, 512, Wkv, 1024, (t >> 4) * 64, (t & 15) * 64,
                   0, ws16, nullptr, 0, nullptr);
  } else {
    int t = id - 144;
    mfma_gemm64<1>(xa, nullptr, 512, Wkv + 512, 1024, (t >> 4) * 64,
                   (t & 15) * 64, 1, ws16, nullptr, 0, nullptr);
  }
}

// K3: out = (hv + ha) @ Wproj.T + bproj. 16 blocks x 256 threads.
__global__ __launch_bounds__(256) void proj_out_kernel(
    const _Float16* __restrict__ ws16, const float* __restrict__ Wproj,
    const float* __restrict__ bproj, float* __restrict__ out)
{
  const float* hv = (const float*)(ws16 + OHOUT16);
  const float* ha = hv + 65536;
  mfma_gemm64<2>(hv, ha, 512, Wproj, 512,
                 (int)(blockIdx.x >> 3) * 64, (int)(blockIdx.x & 7) * 64, 0,
                 nullptr, out, 512, bproj);
}

// ---------------------------------------------------------------------------
// K2: attention, one block per (bh, side) = 32 blocks x 512 threads (8 waves).
// ALL MFMA operands staged to LDS with coalesced 16B-chunk copies + XOR
// chunk swizzle (R7/R9-verified body).
// ---------------------------------------------------------------------------
__global__ __launch_bounds__(512) void attn_kernel(
    const _Float16* __restrict__ ws16, float* __restrict__ hv,
    float* __restrict__ ha)
{
  __shared__ __align__(16) _Float16 smem[55552];   // ~108.5 KB
  _Float16* Kl = smem;            // [256 rows][8 chunks]  32 KB
  _Float16* Vl = smem + 16384;    // [64 rows][32 chunks]  32 KB
  _Float16* Ql = smem + 32768;    // [64 rows][8 chunks]    8 KB
  _Float16* P  = smem + 36864;    // [64 rows][32 chunks]  32 KB
  float* m_s  = (float*)(smem + 53248);   // [8][64]
  float* l_s  = m_s + 512;                // [8][64]
  float* Mtot = l_s + 512;                // [64]
  float* Ltot = Mtot + 64;                // [64]

  const int x = blockIdx.x;       // bh*2 + side
  const int side = x & 1;
  const int bh = x >> 1;
  const int b = bh >> 3, h = bh & 7;

  const int tid = threadIdx.x;
  const int w = tid >> 6;         // wave 0..7
  const int lane = tid & 63;
  const int l15 = lane & 15;
  const int kg = lane >> 4;       // 0..3

  const _Float16* gQ = ws16 + OQ16 + (size_t)bh * 4096;
  const _Float16* gK = ws16 + OK16 + (size_t)side * SIDESZ + (size_t)bh * 16384;
  const _Float16* gV = ws16 + OVT16 + (size_t)side * SIDESZ + (size_t)bh * 16384;

  // ---- coalesced staging (16B/lane contiguous) with XOR chunk swizzle
  {
    int ch = tid;                 // Q: 512 chunks (8 per row)
    int row = ch >> 3, c = ch & 7;
    *reinterpret_cast<f16x8*>(&Ql[row * 64 + ((c ^ (row & 7)) * 8)]) =
        *reinterpret_cast<const f16x8*>(&gQ[ch * 8]);
  }
  #pragma unroll
  for (int i = 0; i < 4; ++i) {   // K: 2048 chunks (8 per row)
    int ch = tid + i * 512;
    int row = ch >> 3, c = ch & 7;
    *reinterpret_cast<f16x8*>(&Kl[row * 64 + ((c ^ (row & 7)) * 8)]) =
        *reinterpret_cast<const f16x8*>(&gK[ch * 8]);
  }
  #pragma unroll
  for (int i = 0; i < 4; ++i) {   // VT: 2048 chunks (32 per row)
    int ch = tid + i * 512;
    int row = ch >> 5, c = ch & 31;
    *reinterpret_cast<f16x8*>(&Vl[row * 256 + ((c ^ (row & 7)) * 8)]) =
        *reinterpret_cast<const f16x8*>(&gV[ch * 8]);
  }
  __syncthreads();

  // ---- QK^T: S^T[key][q] = mfma(K,Q), keys w*32 + kf*16 + l15
  f16x8 qb[4][2];
  #pragma unroll
  for (int qf = 0; qf < 4; ++qf)
    #pragma unroll
    for (int ks = 0; ks < 2; ++ks)
      qb[qf][ks] = *reinterpret_cast<const f16x8*>(
          &Ql[(qf * 16 + l15) * 64 + (((ks * 4 + kg) ^ (l15 & 7)) * 8)]);

  f32x4 st[2][4] = {};
  #pragma unroll
  for (int kf = 0; kf < 2; ++kf) {
    int krow = w * 32 + kf * 16 + l15;
    #pragma unroll
    for (int ks = 0; ks < 2; ++ks) {
      f16x8 af = *reinterpret_cast<const f16x8*>(
          &Kl[krow * 64 + (((ks * 4 + kg) ^ (l15 & 7)) * 8)]);
      #pragma unroll
      for (int qf = 0; qf < 4; ++qf)
        st[kf][qf] = __builtin_amdgcn_mfma_f32_16x16x32_f16(
            af, qb[qf][ks], st[kf][qf], 0, 0, 0);
    }
  }
  // st[kf][qf][r] = S[key=w*32+kf*16+4*kg+r][q=qf*16+l15]

  // ---- per-wave max (32 keys) -> LDS -> global max over 8 waves
  float mx[4];
  #pragma unroll
  for (int qf = 0; qf < 4; ++qf) {
    float m = st[0][qf][0];
    #pragma unroll
    for (int kf = 0; kf < 2; ++kf)
      #pragma unroll
      for (int r = 0; r < 4; ++r) m = fmaxf(m, st[kf][qf][r]);
    m = fmaxf(m, __shfl_xor(m, 16));
    m = fmaxf(m, __shfl_xor(m, 32));
    mx[qf] = m;
  }
  if (kg == 0) {
    #pragma unroll
    for (int qf = 0; qf < 4; ++qf) m_s[w * 64 + qf * 16 + l15] = mx[qf];
  }
  __syncthreads();
  if (tid < 64) {
    float M = m_s[tid];
    #pragma unroll
    for (int w2 = 1; w2 < 8; ++w2) M = fmaxf(M, m_s[w2 * 64 + tid]);
    Mtot[tid] = M;
  }
  __syncthreads();

  // ---- exp, partial sums, P -> swizzled LDS
  #pragma unroll
  for (int qf = 0; qf < 4; ++qf) {
    float M = Mtot[qf * 16 + l15];
    float ls = 0.f;
    #pragma unroll
    for (int kf = 0; kf < 2; ++kf)
      #pragma unroll
      for (int r = 0; r < 4; ++r) {
        float e = __expf(st[kf][qf][r] - M);
        st[kf][qf][r] = e;
        ls += e;
      }
    ls += __shfl_xor(ls, 16);
    ls += __shfl_xor(ls, 32);
    if (kg == 0) l_s[w * 64 + qf * 16 + l15] = ls;
    #pragma unroll
    for (int kf = 0; kf < 2; ++kf) {
      int q = qf * 16 + l15;
      int chunk = w * 4 + kf * 2 + (kg >> 1);
      f16x4 pk = {(_Float16)st[kf][qf][0], (_Float16)st[kf][qf][1],
                  (_Float16)st[kf][qf][2], (_Float16)st[kf][qf][3]};
      *reinterpret_cast<f16x4*>(
          &P[q * 256 + ((chunk ^ (q & 7)) * 8) + (kg & 1) * 4]) = pk;
    }
  }
  __syncthreads();
  if (tid < 64) {
    float L = l_s[tid];
    #pragma unroll
    for (int w2 = 1; w2 < 8; ++w2) L += l_s[w2 * 64 + tid];
    Ltot[tid] = L;
  }
  __syncthreads();

  // ---- PV: wave owns (qf = w&3, d-frags 2*(w>>2)+{0,1}), all 256 keys
  const int qf = w & 3;
  const int d0 = (w >> 2) * 2;
  f32x4 oc[2] = {};
  #pragma unroll
  for (int ks = 0; ks < 8; ++ks) {
    f16x8 pa = *reinterpret_cast<const f16x8*>(
        &P[(qf * 16 + l15) * 256 + (((ks * 4 + kg) ^ (l15 & 7)) * 8)]);
    #pragma unroll
    for (int j = 0; j < 2; ++j) {
      int d = (d0 + j) * 16 + l15;
      f16x8 vb = *reinterpret_cast<const f16x8*>(
          &Vl[d * 256 + (((ks * 4 + kg) ^ (d & 7)) * 8)]);
      oc[j] = __builtin_amdgcn_mfma_f32_16x16x32_f16(pa, vb, oc[j], 0, 0, 0);
    }
  }

  float* houtS = side ? ha : hv;
  #pragma unroll
  for (int j = 0; j < 2; ++j)
    #pragma unroll
    for (int r = 0; r < 4; ++r) {
      int q = qf * 16 + kg * 4 + r;
      int d = (d0 + j) * 16 + l15;
      houtS[(size_t)(b * 64 + q) * 512 + h * 64 + d] =
          oc[j][r] * (1.0f / Ltot[q]);
    }
}

extern "C" void kernel_launch(void* const* d_in, const int* in_sizes, int n_in,
                              void* d_out, int out_size, void* d_ws, size_t ws_size,
                              hipStream_t stream) {
  const float* xmm   = (const float*)d_in[0];  // [2,64,512]
  const float* xa    = (const float*)d_in[1];  // [2,256,512]
  const float* xv    = (const float*)d_in[2];  // [2,256,512]
  const float* Wq    = (const float*)d_in[3];  // [512,512]
  const float* Wkv   = (const float*)d_in[4];  // [1024,1024]
  const float* Wproj = (const float*)d_in[5];  // [512,512]
  const float* bproj = (const float*)d_in[6];  // [512]
  float* out = (float*)d_out;                  // [2,64,512]
  _Float16* ws16 = (_Float16*)d_ws;
  float* hv = (float*)(ws16 + OHOUT16);
  float* ha = hv + 65536;

  fused_proj_kernel<<<272, 256, 0, stream>>>(xmm, xa, xv, Wq, Wkv, ws16);
  attn_kernel<<<32, 512, 0, stream>>>(ws16, hv, ha);
  proj_out_kernel<<<16, 256, 0, stream>>>(ws16, Wproj, bproj, out);
}